// Round 1
// baseline (1213.930 us; speedup 1.0000x reference)
//
#include <hip/hip_runtime.h>

// LSTM_1030792151143: 2-layer LSTM (B=2048, T=1000, F=40, H1=8, H2=6) + tanh + FC + sigmoid.
//
// Round 3 theory: both paths were serializing memory latency into the recurrent chain.
//  - lstm_rec: rolling buf[] prefetch depended on compiler register-renaming across unroll
//    bodies for vmcnt distance; replaced with explicit chunked double-buffer (issue 8 loads
//    at chunk top, consume cur[], copy nxt->cur once per 8 steps -> wait is ~8 steps late).
//  - lstm_fused (runs when ws < 262 MB): x-row loads were wave-uniform -> s_load (SMEM,
//    lgkmcnt). Every __shfl's lgkmcnt(0) wait drained the x prefetch -> HBM latency on the
//    chain EVERY step. Fix: per-lane rotated VMEM loads (vmcnt; invisible to shuffle waits)
//    with identically-rotated W_ih1 registers, double-buffered at ~2-step distance; and
//    LDS h-broadcasts replaced with v_readlane (no DS at all outside the 8 gate shuffles).

constexpr int Bn = 2048, Tn = 1000, Fn = 40;
constexpr int H1n = 8, H2n = 6;
constexpr int G1n = 32, G2n = 24;
constexpr int PF = 8;            // lstm_rec prefetch chunk (steps)
constexpr int NC = Fn / 4;       // 10 float4 chunks per x row

__device__ __forceinline__ float frcp(float x) { return __builtin_amdgcn_rcpf(x); }
__device__ __forceinline__ float act_abc(float A, float Bc, float C, float x) {
    return fmaf(A, frcp(1.0f + __expf(Bc * x)), C);   // sigmoid: (1,-1,0); tanh: (2,-2,-1)
}
__device__ __forceinline__ float ftanh(float x) {
    return fmaf(2.0f, frcp(1.0f + __expf(-2.0f * x)), -1.0f);
}
__device__ __forceinline__ float bcast(float v, int k) {   // lane-k broadcast via readlane
    return __uint_as_float(__builtin_amdgcn_readlane(__float_as_uint(v), k));
}

// ---------------- Pass 1: input projection (no recurrence) ----------------
__global__ __launch_bounds__(256, 8) void xg_pass(
    const float* __restrict__ x, const float* __restrict__ W_ih1,
    const float* __restrict__ b_ih1, const float* __restrict__ b_hh1,
    float* __restrict__ xg)
{
    const int lane  = threadIdx.x & 63;
    const int wslot = __builtin_amdgcn_readfirstlane((int)(threadIdx.x >> 6));
    const int b     = blockIdx.x;                 // 2048 blocks, one batch each
    const int g     = lane & 31;
    constexpr int TC = Tn / 4;                    // 250 steps per wave
    const int t0 = wslot * TC;

    float w[Fn];
#pragma unroll
    for (int k = 0; k < Fn; ++k) w[k] = W_ih1[g * Fn + k];
    const float bias = b_ih1[g] + b_hh1[g];

    const float* __restrict__ xb = x  + (size_t)b * Tn * Fn;
    float* __restrict__       og = xg + (size_t)b * Tn * G1n;

#pragma unroll 2
    for (int t = t0; t < t0 + TC; ++t) {
        const float* __restrict__ row = xb + (size_t)t * Fn;   // wave-uniform -> s_load
        float a0 = bias, a1 = 0.f, a2 = 0.f, a3 = 0.f;
#pragma unroll
        for (int k = 0; k < Fn; k += 4) {
            a0 = fmaf(row[k + 0], w[k + 0], a0);
            a1 = fmaf(row[k + 1], w[k + 1], a1);
            a2 = fmaf(row[k + 2], w[k + 2], a2);
            a3 = fmaf(row[k + 3], w[k + 3], a3);
        }
        if (lane < G1n) og[(size_t)t * G1n + g] = (a0 + a1) + (a2 + a3);
    }
}

// ---------------- Pass 2: recurrence only ----------------
__global__ __launch_bounds__(256, 2) void lstm_rec(
    const float* __restrict__ xg,
    const float* __restrict__ W_hh1,
    const float* __restrict__ W_ih2, const float* __restrict__ W_hh2,
    const float* __restrict__ b_ih2, const float* __restrict__ b_hh2,
    const float* __restrict__ W_fc,  const float* __restrict__ b_fc,
    float* __restrict__ out)
{
    const int lane  = threadIdx.x & 63;
    const int wslot = __builtin_amdgcn_readfirstlane((int)(threadIdx.x >> 6));
    const int b     = blockIdx.x * 4 + wslot;     // 512 blocks * 4 waves

    const int g  = lane & 31;                     // L1 gate owned
    const int g2 = (g < G2n) ? g : (G2n - 1);     // L2 gate (clamped dup)
    const int j1 = lane & 7;
    const int j2 = g % H2n;

    float whh1[H1n];
#pragma unroll
    for (int k = 0; k < H1n; ++k) whh1[k] = W_hh1[g * H1n + k];
    float wih2[H1n];
#pragma unroll
    for (int k = 0; k < H1n; ++k) wih2[k] = W_ih2[g2 * H1n + k];
    float whh2[H2n];
#pragma unroll
    for (int k = 0; k < H2n; ++k) whh2[k] = W_hh2[g2 * H2n + k];
    const float bias2 = b_ih2[g2] + b_hh2[g2];

    const bool t1 = (g >= 16 && g < 24);          // L1 cell gate -> tanh
    const float A1 = t1 ? 2.f : 1.f, Bc1 = t1 ? -2.f : -1.f, C1 = t1 ? -1.f : 0.f;
    const bool t2 = (g2 >= 12 && g2 < 18);        // L2 cell gate -> tanh
    const float A2 = t2 ? 2.f : 1.f, Bc2 = t2 ? -2.f : -1.f, C2 = t2 ? -1.f : 0.f;

    float c1 = 0.f, c2 = 0.f;
    float h1s[H1n], th1s[H1n], h2s[H2n];
#pragma unroll
    for (int k = 0; k < H1n; ++k) { h1s[k] = 0.f; th1s[k] = 0.f; }
#pragma unroll
    for (int k = 0; k < H2n; ++k) h2s[k] = 0.f;

    const float* __restrict__ xgb = xg + (size_t)b * Tn * G1n + g;

    // ---- explicit chunked double-buffer prefetch: the vmcnt wait for a load is
    //      structurally >= 7 steps after its issue, independent of compiler renaming. ----
    float cur[PF], nxt[PF];
#pragma unroll
    for (int i = 0; i < PF; ++i) cur[i] = xgb[(size_t)i * G1n];

    float a_pre = cur[0];                          // t=0: h1=0 so preact = xg

    for (int tc = 0; tc < Tn; tc += PF) {
        // issue the whole next chunk's loads up front (max distance to consumption)
#pragma unroll
        for (int i = 0; i < PF; ++i) {
            int tp = tc + PF + i; if (tp >= Tn) tp = Tn - 1;
            nxt[i] = xgb[(size_t)tp * G1n];
        }

#pragma unroll
        for (int i = 0; i < PF; ++i) {
            // ---- layer 1 gate + state ----
            const float gv  = act_abc(A1, Bc1, C1, a_pre);
            const float iv  = __shfl(gv, j1);
            const float fv  = __shfl(gv, j1 + 8);
            const float gcv = __shfl(gv, j1 + 16);
            const float ov  = __shfl(gv, j1 + 24);
            c1 = fmaf(fv, c1, iv * gcv);
            const float h1v  = ov * ftanh(c1);
            const float th1v = ftanh(h1v);

#pragma unroll
            for (int k = 0; k < H1n; ++k) h1s[k]  = bcast(h1v, k);
#pragma unroll
            for (int k = 0; k < H1n; ++k) th1s[k] = bcast(th1v, k);

            // ---- next-step L1 preactivation (pipelined) ----
            {
                float a0 = (i + 1 < PF) ? cur[i + 1] : nxt[0];   // nxt[0] is ~7 steps old
                float a1 = 0.f;
#pragma unroll
                for (int k = 0; k < H1n; k += 2) {
                    a0 = fmaf(h1s[k],     whh1[k],     a0);
                    a1 = fmaf(h1s[k + 1], whh1[k + 1], a1);
                }
                a_pre = a0 + a1;
            }

            // ---- layer 2 full step ----
            float a20 = bias2, a21 = 0.f;
#pragma unroll
            for (int k = 0; k < H1n; k += 2) {
                a20 = fmaf(th1s[k],     wih2[k],     a20);
                a21 = fmaf(th1s[k + 1], wih2[k + 1], a21);
            }
#pragma unroll
            for (int k = 0; k < H2n; k += 2) {
                a20 = fmaf(h2s[k],     whh2[k],     a20);
                a21 = fmaf(h2s[k + 1], whh2[k + 1], a21);
            }
            const float gv2  = act_abc(A2, Bc2, C2, a20 + a21);
            const float iv2  = __shfl(gv2, j2);
            const float fv2  = __shfl(gv2, j2 + 6);
            const float gcv2 = __shfl(gv2, j2 + 12);
            const float ov2  = __shfl(gv2, j2 + 18);
            c2 = fmaf(fv2, c2, iv2 * gcv2);
            const float h2v = ov2 * ftanh(c2);

#pragma unroll
            for (int k = 0; k < H2n; ++k) h2s[k] = bcast(h2v, k);
        }

        // rotate buffers — single wait point per 8 steps, loads are a full chunk old
#pragma unroll
        for (int i = 0; i < PF; ++i) cur[i] = nxt[i];
    }

    if (lane == 0) {
        float a = b_fc[0];
#pragma unroll
        for (int k = 0; k < H2n; ++k) a = fmaf(ftanh(h2s[k]), W_fc[k], a);
        out[b] = frcp(1.0f + __expf(-a));
    }
}

// ---------------- Fused fallback (runs if ws too small) ----------------
// Per-lane VMEM x loads (lane-rotated chunks so addresses are divergent -> global_load,
// vmcnt) + readlane broadcasts. No LDS; only DS ops are the 8 gate bpermutes per step.
__global__ __launch_bounds__(256, 2) void lstm_fused(
    const float* __restrict__ x,
    const float* __restrict__ W_ih1, const float* __restrict__ W_hh1,
    const float* __restrict__ b_ih1, const float* __restrict__ b_hh1,
    const float* __restrict__ W_ih2, const float* __restrict__ W_hh2,
    const float* __restrict__ b_ih2, const float* __restrict__ b_hh2,
    const float* __restrict__ W_fc,  const float* __restrict__ b_fc,
    float* __restrict__ out)
{
    const int lane  = threadIdx.x & 63;
    const int wslot = __builtin_amdgcn_readfirstlane((int)(threadIdx.x >> 6));
    const int b     = blockIdx.x * 4 + wslot;

    const int g  = lane & 31;
    const int g2 = (g < G2n) ? g : (G2n - 1);
    const int j1 = lane & 7;
    const int j2 = g % H2n;

    // per-lane chunk rotation: lane l reads x-row float4 chunk (c + l) % NC into slot c.
    // W_ih1 is loaded with the SAME permutation, so the dot product is order-invariant.
    const int rot = lane % NC;
    int offs[NC];                                  // element offsets, per lane
#pragma unroll
    for (int c = 0; c < NC; ++c) {
        int p = c + rot; if (p >= NC) p -= NC;
        offs[c] = p * 4;
    }

    float wih1[Fn];                                // permuted to match offs[]
#pragma unroll
    for (int c = 0; c < NC; ++c)
#pragma unroll
        for (int m = 0; m < 4; ++m)
            wih1[c * 4 + m] = W_ih1[g * Fn + offs[c] + m];

    float whh1[H1n];
#pragma unroll
    for (int k = 0; k < H1n; ++k) whh1[k] = W_hh1[g * H1n + k];
    const float bias1 = b_ih1[g] + b_hh1[g];

    float wih2[H1n];
#pragma unroll
    for (int k = 0; k < H1n; ++k) wih2[k] = W_ih2[g2 * H1n + k];
    float whh2[H2n];
#pragma unroll
    for (int k = 0; k < H2n; ++k) whh2[k] = W_hh2[g2 * H2n + k];
    const float bias2 = b_ih2[g2] + b_hh2[g2];

    const bool t1 = (g >= 16 && g < 24);
    const float A1 = t1 ? 2.f : 1.f, Bc1 = t1 ? -2.f : -1.f, C1 = t1 ? -1.f : 0.f;
    const bool t2 = (g2 >= 12 && g2 < 18);
    const float A2 = t2 ? 2.f : 1.f, Bc2 = t2 ? -2.f : -1.f, C2 = t2 ? -1.f : 0.f;

    float h1s[H1n], th1s[H1n], h2s[H2n];
#pragma unroll
    for (int k = 0; k < H1n; ++k) { h1s[k] = 0.f; th1s[k] = 0.f; }
#pragma unroll
    for (int k = 0; k < H2n; ++k) h2s[k] = 0.f;
    float c1 = 0.f, c2 = 0.f;

    const float* __restrict__ xb = x + (size_t)b * Tn * Fn;

    float r0[Fn], r1[Fn];                          // double-buffered prefetch rows
    float xgv;
    {   // row 0 -> xgv directly
        float xr[Fn];
#pragma unroll
        for (int c = 0; c < NC; ++c) {
            const float4 v = *(const float4*)(xb + offs[c]);
            xr[c*4] = v.x; xr[c*4+1] = v.y; xr[c*4+2] = v.z; xr[c*4+3] = v.w;
        }
        float a0 = bias1, a1 = 0.f, a2 = 0.f, a3 = 0.f;
#pragma unroll
        for (int k = 0; k < Fn; k += 4) {
            a0 = fmaf(xr[k],     wih1[k],     a0);
            a1 = fmaf(xr[k + 1], wih1[k + 1], a1);
            a2 = fmaf(xr[k + 2], wih1[k + 2], a2);
            a3 = fmaf(xr[k + 3], wih1[k + 3], a3);
        }
        xgv = (a0 + a1) + (a2 + a3);
    }
    {   // row 1 -> r1 (consumed at bottom of step 0)
        const float* __restrict__ rowp = xb + Fn;
#pragma unroll
        for (int c = 0; c < NC; ++c) {
            const float4 v = *(const float4*)(rowp + offs[c]);
            r1[c*4] = v.x; r1[c*4+1] = v.y; r1[c*4+2] = v.z; r1[c*4+3] = v.w;
        }
    }

#define FUSED_STEP(T, LD, RD)                                                  \
    {                                                                          \
        const int tl = ((T) + 2 < Tn) ? ((T) + 2) : (Tn - 1);                  \
        const float* __restrict__ rowp = xb + (size_t)tl * Fn;                 \
        _Pragma("unroll")                                                      \
        for (int c = 0; c < NC; ++c) {                                         \
            const float4 v = *(const float4*)(rowp + offs[c]);                 \
            LD[c*4] = v.x; LD[c*4+1] = v.y; LD[c*4+2] = v.z; LD[c*4+3] = v.w;  \
        }                                                                      \
        float a = xgv;                                                         \
        _Pragma("unroll")                                                      \
        for (int k = 0; k < H1n; ++k) a = fmaf(h1s[k], whh1[k], a);            \
        const float gv = act_abc(A1, Bc1, C1, a);                              \
        const float iv  = __shfl(gv, j1);                                      \
        const float fv  = __shfl(gv, j1 + 8);                                  \
        const float gcv = __shfl(gv, j1 + 16);                                 \
        const float ov  = __shfl(gv, j1 + 24);                                 \
        c1 = fmaf(fv, c1, iv * gcv);                                           \
        const float h1v  = ov * ftanh(c1);                                     \
        const float th1v = ftanh(h1v);                                         \
        _Pragma("unroll")                                                      \
        for (int k = 0; k < H1n; ++k) h1s[k]  = bcast(h1v, k);                 \
        _Pragma("unroll")                                                      \
        for (int k = 0; k < H1n; ++k) th1s[k] = bcast(th1v, k);                \
        float a20 = bias2, a21 = 0.f;                                          \
        _Pragma("unroll")                                                      \
        for (int k = 0; k < H1n; k += 2) {                                     \
            a20 = fmaf(th1s[k],     wih2[k],     a20);                         \
            a21 = fmaf(th1s[k + 1], wih2[k + 1], a21);                         \
        }                                                                      \
        _Pragma("unroll")                                                      \
        for (int k = 0; k < H2n; k += 2) {                                     \
            a20 = fmaf(h2s[k],     whh2[k],     a20);                          \
            a21 = fmaf(h2s[k + 1], whh2[k + 1], a21);                          \
        }                                                                      \
        const float gv2 = act_abc(A2, Bc2, C2, a20 + a21);                     \
        const float iv2  = __shfl(gv2, j2);                                    \
        const float fv2  = __shfl(gv2, j2 + 6);                                \
        const float gcv2 = __shfl(gv2, j2 + 12);                               \
        const float ov2  = __shfl(gv2, j2 + 18);                               \
        c2 = fmaf(fv2, c2, iv2 * gcv2);                                        \
        const float h2v = ov2 * ftanh(c2);                                     \
        _Pragma("unroll")                                                      \
        for (int k = 0; k < H2n; ++k) h2s[k] = bcast(h2v, k);                  \
        float b0 = bias1, b1 = 0.f, b2 = 0.f, b3 = 0.f;                        \
        _Pragma("unroll")                                                      \
        for (int k = 0; k < Fn; k += 4) {                                      \
            b0 = fmaf(RD[k],     wih1[k],     b0);                             \
            b1 = fmaf(RD[k + 1], wih1[k + 1], b1);                             \
            b2 = fmaf(RD[k + 2], wih1[k + 2], b2);                             \
            b3 = fmaf(RD[k + 3], wih1[k + 3], b3);                             \
        }                                                                      \
        xgv = (b0 + b1) + (b2 + b3);                                           \
    }

    for (int t = 0; t < Tn; t += 2) {
        FUSED_STEP(t,     r0, r1);    // loads row t+2 -> r0, consumes r1 = row t+1
        FUSED_STEP(t + 1, r1, r0);    // loads row t+3 -> r1, consumes r0 = row t+2
    }
#undef FUSED_STEP

    if (lane == 0) {
        float a = b_fc[0];
#pragma unroll
        for (int k = 0; k < H2n; ++k) a = fmaf(ftanh(h2s[k]), W_fc[k], a);
        out[b] = frcp(1.0f + __expf(-a));
    }
}

extern "C" void kernel_launch(void* const* d_in, const int* in_sizes, int n_in,
                              void* d_out, int out_size, void* d_ws, size_t ws_size,
                              hipStream_t stream) {
    (void)in_sizes; (void)n_in; (void)out_size;
    const float* x     = (const float*)d_in[0];
    const float* W_ih1 = (const float*)d_in[1];
    const float* W_hh1 = (const float*)d_in[2];
    const float* b_ih1 = (const float*)d_in[3];
    const float* b_hh1 = (const float*)d_in[4];
    const float* W_ih2 = (const float*)d_in[5];
    const float* W_hh2 = (const float*)d_in[6];
    const float* b_ih2 = (const float*)d_in[7];
    const float* b_hh2 = (const float*)d_in[8];
    const float* W_fc  = (const float*)d_in[9];
    const float* b_fc  = (const float*)d_in[10];
    float* out = (float*)d_out;

    const size_t need = (size_t)Bn * Tn * G1n * sizeof(float);   // 262 MB
    if (ws_size >= need) {
        float* xg = (float*)d_ws;
        xg_pass<<<dim3(Bn), dim3(256), 0, stream>>>(x, W_ih1, b_ih1, b_hh1, xg);
        lstm_rec<<<dim3(Bn / 4), dim3(256), 0, stream>>>(xg, W_hh1, W_ih2, W_hh2,
                                                         b_ih2, b_hh2, W_fc, b_fc, out);
    } else {
        lstm_fused<<<dim3(Bn / 4), dim3(256), 0, stream>>>(x, W_ih1, W_hh1, b_ih1, b_hh1,
                                                           W_ih2, W_hh2, b_ih2, b_hh2,
                                                           W_fc, b_fc, out);
    }
}

// Round 2
// 983.144 us; speedup vs baseline: 1.2347x; 1.2347x over previous
//
#include <hip/hip_runtime.h>

// LSTM_1030792151143: 2-layer LSTM (B=2048, T=1000, F=40, H1=8, H2=6) + tanh + FC + sigmoid.
//
// Round 4: in-block producer/consumer pipeline.
//   rocprof r1: xg_pass = 508 us at 14.5% HBM peak, VALUBusy 15% -> latency-bound on
//   wave-uniform s_load x rows; traffic was already ideal. Instead of retuning it,
//   fuse: block = 2 batches; waves 0,1 = consumers (recurrence, 1 batch each),
//   waves 2,3 = producers (xg for the NEXT 32-step tile into LDS, 1 batch each).
//   x staged global->LDS coalesced (float4), xg double-buffered in LDS, __syncthreads
//   per phase. Removes 262MB xg write + 262MB re-read, hides all xg compute under the
//   recurrence (producer slack ~2.5x), and decouples the consumer from HBM entirely.
//   Consumer math is the verified lstm_rec body (absmax 0.0); xg feed is one trailing
//   ds_read per step placed AFTER the gate bpermutes so counted lgkmcnt waits don't
//   drain it; a_pre split as (xgv + hdot) so the tile-boundary read sits after the
//   barrier.

constexpr int Bn = 2048, Tn = 1000, Fn = 40;
constexpr int H1n = 8, H2n = 6;
constexpr int G1n = 32, G2n = 24;
constexpr int TT  = 32;                     // time-steps per pipeline tile
constexpr int NT  = (Tn + TT - 1) / TT;     // 32 tiles (last has 8 rows)

__device__ __forceinline__ float frcp(float x) { return __builtin_amdgcn_rcpf(x); }
__device__ __forceinline__ float act_abc(float A, float Bc, float C, float x) {
    return fmaf(A, frcp(1.0f + __expf(Bc * x)), C);   // sigmoid: (1,-1,0); tanh: (2,-2,-1)
}
__device__ __forceinline__ float ftanh(float x) {
    return fmaf(2.0f, frcp(1.0f + __expf(-2.0f * x)), -1.0f);
}
__device__ __forceinline__ float bcast(float v, int k) {   // lane-k broadcast
    return __uint_as_float(__builtin_amdgcn_readlane(__float_as_uint(v), k));
}

__global__ __launch_bounds__(256, 4) void lstm_pipe(
    const float* __restrict__ x,
    const float* __restrict__ W_ih1, const float* __restrict__ W_hh1,
    const float* __restrict__ b_ih1, const float* __restrict__ b_hh1,
    const float* __restrict__ W_ih2, const float* __restrict__ W_hh2,
    const float* __restrict__ b_ih2, const float* __restrict__ b_hh2,
    const float* __restrict__ W_fc,  const float* __restrict__ b_fc,
    float* __restrict__ out)
{
    __shared__ float s_x [2][TT * Fn];          // staged x rows, one buffer per batch-slot
    __shared__ float s_xg[2][2][TT * G1n];      // xg tiles, double-buffered per batch-slot

    const int lane  = threadIdx.x & 63;
    const int wslot = __builtin_amdgcn_readfirstlane((int)(threadIdx.x >> 6));
    const int bi    = wslot & 1;                 // batch slot within block
    const int b     = blockIdx.x * 2 + bi;       // 1024 blocks * 2 batches
    const int g     = lane & 31;

    if (wslot >= 2) {
        // ---------------- producer: xg for tile p into s_xg[bi][p&1] ----------------
        float wih1[Fn];
#pragma unroll
        for (int k = 0; k < Fn; ++k) wih1[k] = W_ih1[g * Fn + k];
        const float bias1 = b_ih1[g] + b_hh1[g];

        const char*  xcb  = (const char*)(x + (size_t)b * Tn * Fn);
        const size_t omax = (size_t)Tn * Fn * 4 - 16;     // last valid 16B chunk in batch

        for (int p = 0; p <= NT; ++p) {
            if (p < NT) {
                const int t0   = p * TT;
                const int rows = (Tn - t0 < TT) ? (Tn - t0) : TT;

                // stage x tile (rows*160B, <=5120B) coalesced: 5 x (64 lanes * 16B)
                {
                    float4 v[5];
                    const size_t base = (size_t)t0 * Fn * 4;
#pragma unroll
                    for (int i = 0; i < 5; ++i) {
                        size_t o = base + (size_t)(i * 1024 + lane * 16);
                        if (o > omax) o = omax;            // tail clamp, stays in batch
                        v[i] = *(const float4*)(xcb + o);
                    }
                    char* sx = (char*)&s_x[bi][0];
#pragma unroll
                    for (int i = 0; i < 5; ++i)
                        *(float4*)(sx + i * 1024 + lane * 16) = v[i];
                }

                // compute xg rows: lane g owns gate g; x row via uniform-addr ds_read
                float* xo = &s_xg[bi][p & 1][0];
                for (int r = 0; r < rows; ++r) {
                    const float* xr = &s_x[bi][r * Fn];
                    float a0 = bias1, a1 = 0.f, a2 = 0.f, a3 = 0.f;
#pragma unroll
                    for (int k = 0; k < Fn; k += 4) {
                        const float4 c = *(const float4*)&xr[k];
                        a0 = fmaf(c.x, wih1[k],     a0);
                        a1 = fmaf(c.y, wih1[k + 1], a1);
                        a2 = fmaf(c.z, wih1[k + 2], a2);
                        a3 = fmaf(c.w, wih1[k + 3], a3);
                    }
                    if (lane < G1n) xo[r * G1n + g] = (a0 + a1) + (a2 + a3);
                }
            }
            __syncthreads();
        }
    } else {
        // ---------------- consumer: recurrence for batch b ----------------
        const int g2 = (g < G2n) ? g : (G2n - 1);
        const int j1 = lane & 7;
        const int j2 = g % H2n;

        float whh1[H1n];
#pragma unroll
        for (int k = 0; k < H1n; ++k) whh1[k] = W_hh1[g * H1n + k];
        float wih2[H1n];
#pragma unroll
        for (int k = 0; k < H1n; ++k) wih2[k] = W_ih2[g2 * H1n + k];
        float whh2[H2n];
#pragma unroll
        for (int k = 0; k < H2n; ++k) whh2[k] = W_hh2[g2 * H2n + k];
        const float bias2 = b_ih2[g2] + b_hh2[g2];

        const bool t1 = (g >= 16 && g < 24);          // L1 cell gate -> tanh
        const float A1 = t1 ? 2.f : 1.f, Bc1 = t1 ? -2.f : -1.f, C1 = t1 ? -1.f : 0.f;
        const bool t2 = (g2 >= 12 && g2 < 18);        // L2 cell gate -> tanh
        const float A2 = t2 ? 2.f : 1.f, Bc2 = t2 ? -2.f : -1.f, C2 = t2 ? -1.f : 0.f;

        float c1 = 0.f, c2 = 0.f, hdot = 0.f;
        float h1s[H1n], th1s[H1n], h2s[H2n];
#pragma unroll
        for (int k = 0; k < H1n; ++k) { h1s[k] = 0.f; th1s[k] = 0.f; }
#pragma unroll
        for (int k = 0; k < H2n; ++k) h2s[k] = 0.f;

        for (int p = 0; p <= NT; ++p) {
            if (p >= 1) {
                const int tile = p - 1;
                const int rows = (Tn - tile * TT < TT) ? (Tn - tile * TT) : TT;
                const float* xgt = &s_xg[bi][tile & 1][0];

                float xgv = xgt[g];                   // row 0 (written last phase)
                for (int i = 0; i < rows; ++i) {
                    // ---- layer 1 ----
                    const float a_pre = xgv + hdot;   // hdot = sum h1(t-1)*Whh1
                    const float gv  = act_abc(A1, Bc1, C1, a_pre);
                    const float iv  = __shfl(gv, j1);
                    const float fv  = __shfl(gv, j1 + 8);
                    const float gcv = __shfl(gv, j1 + 16);
                    const float ov  = __shfl(gv, j1 + 24);
                    c1 = fmaf(fv, c1, iv * gcv);
                    const float h1v  = ov * ftanh(c1);
                    const float th1v = ftanh(h1v);

#pragma unroll
                    for (int k = 0; k < H1n; ++k) h1s[k]  = bcast(h1v, k);
#pragma unroll
                    for (int k = 0; k < H1n; ++k) th1s[k] = bcast(th1v, k);

                    {   // next-step recurrent dot (xg added next step)
                        float a0 = 0.f, a1 = 0.f;
#pragma unroll
                        for (int k = 0; k < H1n; k += 2) {
                            a0 = fmaf(h1s[k],     whh1[k],     a0);
                            a1 = fmaf(h1s[k + 1], whh1[k + 1], a1);
                        }
                        hdot = a0 + a1;
                    }

                    // ---- layer 2 ----
                    float a20 = bias2, a21 = 0.f;
#pragma unroll
                    for (int k = 0; k < H1n; k += 2) {
                        a20 = fmaf(th1s[k],     wih2[k],     a20);
                        a21 = fmaf(th1s[k + 1], wih2[k + 1], a21);
                    }
#pragma unroll
                    for (int k = 0; k < H2n; k += 2) {
                        a20 = fmaf(h2s[k],     whh2[k],     a20);
                        a21 = fmaf(h2s[k + 1], whh2[k + 1], a21);
                    }
                    const float gv2  = act_abc(A2, Bc2, C2, a20 + a21);
                    const float iv2  = __shfl(gv2, j2);
                    const float fv2  = __shfl(gv2, j2 + 6);
                    const float gcv2 = __shfl(gv2, j2 + 12);
                    const float ov2  = __shfl(gv2, j2 + 18);
                    c2 = fmaf(fv2, c2, iv2 * gcv2);
                    const float h2v = ov2 * ftanh(c2);

#pragma unroll
                    for (int k = 0; k < H2n; ++k) h2s[k] = bcast(h2v, k);

                    // prefetch next step's xg AFTER all bpermutes of this step, so the
                    // shuffles' counted lgkmcnt waits don't drain it; consumed next iter.
                    xgv = (i + 1 < rows) ? xgt[(size_t)(i + 1) * G1n + g] : 0.f;
                }
            }
            __syncthreads();
        }

        if (lane == 0) {
            float a = b_fc[0];
#pragma unroll
            for (int k = 0; k < H2n; ++k) a = fmaf(ftanh(h2s[k]), W_fc[k], a);
            out[b] = frcp(1.0f + __expf(-a));
        }
    }
}

extern "C" void kernel_launch(void* const* d_in, const int* in_sizes, int n_in,
                              void* d_out, int out_size, void* d_ws, size_t ws_size,
                              hipStream_t stream) {
    (void)in_sizes; (void)n_in; (void)out_size; (void)d_ws; (void)ws_size;
    const float* x     = (const float*)d_in[0];
    const float* W_ih1 = (const float*)d_in[1];
    const float* W_hh1 = (const float*)d_in[2];
    const float* b_ih1 = (const float*)d_in[3];
    const float* b_hh1 = (const float*)d_in[4];
    const float* W_ih2 = (const float*)d_in[5];
    const float* W_hh2 = (const float*)d_in[6];
    const float* b_ih2 = (const float*)d_in[7];
    const float* b_hh2 = (const float*)d_in[8];
    const float* W_fc  = (const float*)d_in[9];
    const float* b_fc  = (const float*)d_in[10];
    float* out = (float*)d_out;

    lstm_pipe<<<dim3(Bn / 2), dim3(256), 0, stream>>>(x, W_ih1, W_hh1, b_ih1, b_hh1,
                                                      W_ih2, W_hh2, b_ih2, b_hh2,
                                                      W_fc, b_fc, out);
}

// Round 4
// 794.168 us; speedup vs baseline: 1.5286x; 1.2380x over previous
//
#include <hip/hip_runtime.h>

// LSTM_1030792151143: 2-layer LSTM (B=2048, T=1000, F=40, H1=8, H2=6) + tanh + FC + sigmoid.
//
// Round 6 = round 5 resubmitted verbatim (round-3 bench was an infra failure:
// "MI355X container failed twice"; no counters. Kernel re-audited: bounds, swizzle imm,
// barrier parity, LDS size, layout match — no defect found).
//
// Round 5 design: unit-per-lane consumer (8 batches/wave).
//   Evidence: round-1 lstm_rec ~706us == round-2 lstm_pipe 704us -> xg feed is off-chain;
//   the wall is the per-step serial chain (1690 cy/step): act -> 4 bpermute -> c1 -> tanh
//   -> 16 readlane -> dot -> act2 -> 4 bpermute, with lanes 32-63 duplicating everything.
//   New consumer: lane = (batch q, unit j). Each lane computes all 4 gates of its unit
//   locally (no gather between preact and c-update; static activation types). Cross-lane
//   traffic = broadcast h1/th1/h2 within 8-lane groups: 22 ds_swizzle (one DS trip/step,
//   h2s-partial dot fills the latency). xg arrives as ONE ds_read_b128/step from a
//   [t][q][j][gate] LDS layout written by producers. 8 batches/wave -> 256 blocks
//   (1/CU), block = 1 consumer wave + 3 producer waves, 50 tiles x 20 steps.

constexpr int Bn = 2048, Tn = 1000, Fn = 40;
constexpr int H1n = 8, H2n = 6;
constexpr int TT  = 20;                 // rows per tile (50 * 20 = 1000, no tail)
constexpr int NTt = Tn / TT;            // 50 tiles
constexpr int BW  = 8;                  // batches per block (= per consumer wave)

__device__ __forceinline__ float frcp(float x) { return __builtin_amdgcn_rcpf(x); }
__device__ __forceinline__ float fsig(float x) { return frcp(1.0f + __expf(-x)); }
__device__ __forceinline__ float ftanh(float x) {
    return fmaf(2.0f, frcp(1.0f + __expf(-2.0f * x)), -1.0f);
}

// broadcast lane ((lane & 0x18) | K) within each 32-lane half: groups of 8 lanes.
template <int K>
__device__ __forceinline__ float bswz(float v) {
    return __int_as_float(__builtin_amdgcn_ds_swizzle(__float_as_int(v), (K << 5) | 0x18));
}

__global__ __launch_bounds__(256, 1) void lstm_upl(
    const float* __restrict__ x,
    const float* __restrict__ W_ih1, const float* __restrict__ W_hh1,
    const float* __restrict__ b_ih1, const float* __restrict__ b_hh1,
    const float* __restrict__ W_ih2, const float* __restrict__ W_hh2,
    const float* __restrict__ b_ih2, const float* __restrict__ b_hh2,
    const float* __restrict__ W_fc,  const float* __restrict__ b_fc,
    float* __restrict__ out)
{
    __shared__ float s_x [2][BW][TT][Fn];        // 51200 B  (x tiles, staged 1 ahead)
    __shared__ float s_xg[2][TT][BW][32];        // 40960 B  (xg in [t][q][j][gate] layout)

    const int lane  = threadIdx.x & 63;
    const int wslot = __builtin_amdgcn_readfirstlane((int)(threadIdx.x >> 6));
    const int b0    = blockIdx.x * BW;

    // Schedule (52 phases, p = 0..51):
    //   producers: stage x tile p -> s_x[p&1]         (p < 50)
    //              xg tile p-1: s_x[(p-1)&1] -> s_xg[(p-1)&1]   (1 <= p <= 50)
    //   consumer : run tile p-2 from s_xg[(p-2)&1]    (p >= 2)

    if (wslot == 0) {
        // ---------------- consumer: 8 batches, unit-per-lane ----------------
        const int q  = lane >> 3;                 // batch in block
        const int j  = lane & 7;                  // L1 hidden unit
        const int j2 = (j < H2n) ? j : (H2n - 1); // L2 unit (lanes 6,7 duplicate unit 5)

        // L1 recurrent weights: rows j (i), 8+j (f), 16+j (g), 24+j (o)
        float wi1[H1n], wf1[H1n], wg1[H1n], wo1[H1n];
#pragma unroll
        for (int k = 0; k < H1n; ++k) {
            wi1[k] = W_hh1[(     j) * H1n + k];
            wf1[k] = W_hh1[( 8 + j) * H1n + k];
            wg1[k] = W_hh1[(16 + j) * H1n + k];
            wo1[k] = W_hh1[(24 + j) * H1n + k];
        }
        // L2 input weights (from tanh(h1)): rows j2, 6+j2, 12+j2, 18+j2
        float wi2[H1n], wf2[H1n], wg2[H1n], wo2[H1n];
#pragma unroll
        for (int k = 0; k < H1n; ++k) {
            wi2[k] = W_ih2[(     j2) * H1n + k];
            wf2[k] = W_ih2[( 6 + j2) * H1n + k];
            wg2[k] = W_ih2[(12 + j2) * H1n + k];
            wo2[k] = W_ih2[(18 + j2) * H1n + k];
        }
        // L2 recurrent weights
        float vi2[H2n], vf2[H2n], vg2[H2n], vo2[H2n];
#pragma unroll
        for (int k = 0; k < H2n; ++k) {
            vi2[k] = W_hh2[(     j2) * H2n + k];
            vf2[k] = W_hh2[( 6 + j2) * H2n + k];
            vg2[k] = W_hh2[(12 + j2) * H2n + k];
            vo2[k] = W_hh2[(18 + j2) * H2n + k];
        }
        const float bi2c = b_ih2[     j2] + b_hh2[     j2];
        const float bf2c = b_ih2[ 6 + j2] + b_hh2[ 6 + j2];
        const float bg2c = b_ih2[12 + j2] + b_hh2[12 + j2];
        const float bo2c = b_ih2[18 + j2] + b_hh2[18 + j2];

        float wfc[H2n];
#pragma unroll
        for (int k = 0; k < H2n; ++k) wfc[k] = W_fc[k];
        const float bfc = b_fc[0];

        float c1 = 0.f, c2 = 0.f;
        float h1s[H1n], th1s[H1n], h2s[H2n];
#pragma unroll
        for (int k = 0; k < H1n; ++k) { h1s[k] = 0.f; th1s[k] = 0.f; }
#pragma unroll
        for (int k = 0; k < H2n; ++k) h2s[k] = 0.f;

        const int myoff = q * 32 + j * 4;         // float offset of this lane's 4 gates

        for (int p = 0; p <= NTt + 1; ++p) {
            if (p >= 2) {
                const float* xgt = &s_xg[(p - 2) & 1][0][0][0];
                float4 xg4 = *(const float4*)(xgt + myoff);          // row 0 (sync)
                for (int i = 0; i < TT; ++i) {
                    // prefetch next row's gates (consumed next iteration)
                    const int in = (i + 1 < TT) ? (i + 1) : i;
                    const float4 xgn = *(const float4*)(xgt + in * (BW * 32) + myoff);

                    // ---- L1: 4 gate dots (h1s from prev step's swizzles) ----
                    float ai0 = xg4.x, ai1 = 0.f, af0 = xg4.y, af1 = 0.f;
                    float ag0 = xg4.z, ag1 = 0.f, ao0 = xg4.w, ao1 = 0.f;
#pragma unroll
                    for (int k = 0; k < H1n; k += 2) {
                        ai0 = fmaf(h1s[k], wi1[k], ai0); ai1 = fmaf(h1s[k+1], wi1[k+1], ai1);
                        af0 = fmaf(h1s[k], wf1[k], af0); af1 = fmaf(h1s[k+1], wf1[k+1], af1);
                        ag0 = fmaf(h1s[k], wg1[k], ag0); ag1 = fmaf(h1s[k+1], wg1[k+1], ag1);
                        ao0 = fmaf(h1s[k], wo1[k], ao0); ao1 = fmaf(h1s[k+1], wo1[k+1], ao1);
                    }
                    const float iv = fsig (ai0 + ai1);
                    const float fv = fsig (af0 + af1);
                    const float gv = ftanh(ag0 + ag1);
                    const float ov = fsig (ao0 + ao1);
                    c1 = fmaf(fv, c1, iv * gv);
                    const float h1v  = ov * ftanh(c1);
                    const float th1v = ftanh(h1v);

                    // ---- one swizzle trip: broadcast h1/th1 within the 8-lane group ----
                    h1s[0] = bswz<0>(h1v); h1s[1] = bswz<1>(h1v);
                    h1s[2] = bswz<2>(h1v); h1s[3] = bswz<3>(h1v);
                    h1s[4] = bswz<4>(h1v); h1s[5] = bswz<5>(h1v);
                    h1s[6] = bswz<6>(h1v); h1s[7] = bswz<7>(h1v);
                    th1s[0] = bswz<0>(th1v); th1s[1] = bswz<1>(th1v);
                    th1s[2] = bswz<2>(th1v); th1s[3] = bswz<3>(th1v);
                    th1s[4] = bswz<4>(th1v); th1s[5] = bswz<5>(th1v);
                    th1s[6] = bswz<6>(th1v); th1s[7] = bswz<7>(th1v);

                    // ---- L2: h2s-partials first (fills the swizzle latency) ----
                    float bi0 = bi2c, bi1 = 0.f, bf0 = bf2c, bf1 = 0.f;
                    float bg0 = bg2c, bg1 = 0.f, bo0 = bo2c, bo1 = 0.f;
#pragma unroll
                    for (int k = 0; k < H2n; k += 2) {
                        bi0 = fmaf(h2s[k], vi2[k], bi0); bi1 = fmaf(h2s[k+1], vi2[k+1], bi1);
                        bf0 = fmaf(h2s[k], vf2[k], bf0); bf1 = fmaf(h2s[k+1], vf2[k+1], bf1);
                        bg0 = fmaf(h2s[k], vg2[k], bg0); bg1 = fmaf(h2s[k+1], vg2[k+1], bg1);
                        bo0 = fmaf(h2s[k], vo2[k], bo0); bo1 = fmaf(h2s[k+1], vo2[k+1], bo1);
                    }
#pragma unroll
                    for (int k = 0; k < H1n; k += 2) {
                        bi0 = fmaf(th1s[k], wi2[k], bi0); bi1 = fmaf(th1s[k+1], wi2[k+1], bi1);
                        bf0 = fmaf(th1s[k], wf2[k], bf0); bf1 = fmaf(th1s[k+1], wf2[k+1], bf1);
                        bg0 = fmaf(th1s[k], wg2[k], bg0); bg1 = fmaf(th1s[k+1], wg2[k+1], bg1);
                        bo0 = fmaf(th1s[k], wo2[k], bo0); bo1 = fmaf(th1s[k+1], wo2[k+1], bo1);
                    }
                    const float i2v = fsig (bi0 + bi1);
                    const float f2v = fsig (bf0 + bf1);
                    const float g2v = ftanh(bg0 + bg1);
                    const float o2v = fsig (bo0 + bo1);
                    c2 = fmaf(f2v, c2, i2v * g2v);
                    const float h2v = o2v * ftanh(c2);

                    h2s[0] = bswz<0>(h2v); h2s[1] = bswz<1>(h2v);
                    h2s[2] = bswz<2>(h2v); h2s[3] = bswz<3>(h2v);
                    h2s[4] = bswz<4>(h2v); h2s[5] = bswz<5>(h2v);

                    xg4 = xgn;
                }
            }
            __syncthreads();
        }

        if (j == 0) {                              // lanes 0,8,...,56 -> out[b0 + q]
            float a = bfc;
#pragma unroll
            for (int k = 0; k < H2n; ++k) a = fmaf(ftanh(h2s[k]), wfc[k], a);
            out[b0 + q] = fsig(a);
        }
    } else {
        // ---------------- producers: stage x + compute xg, one tile ahead ----------------
        const int wp = wslot - 1;                  // 0..2
        const int g  = lane & 31;                  // gate owned
        const int qh = (lane >> 5) * 4;            // batch quad: 0-3 or 4-7
        const int jj = g & 7, ss = g >> 3;         // unit, gate-selector

        float wih1[Fn];
#pragma unroll
        for (int k = 0; k < Fn; ++k) wih1[k] = W_ih1[g * Fn + k];
        const float bias1 = b_ih1[g] + b_hh1[g];

        const char* xcb = (const char*)x;

        for (int p = 0; p <= NTt + 1; ++p) {
            // stage x tile p -> s_x[p&1]: 25 KiB = 25 chunks of (64 lanes x 16B)
            if (p < NTt) {
                float4 vv[9];
#pragma unroll
                for (int ci = 0; ci < 9; ++ci) {
                    const int c = wp + ci * 3;
                    if (c < 25) {
                        const int o   = c * 1024 + lane * 16;   // byte offset in s_x tile
                        const int qq  = o / 3200;               // batch (3200 B per batch)
                        const int rem = o - qq * 3200;          // r*160 + f*4
                        vv[ci] = *(const float4*)(xcb
                                   + (size_t)(b0 + qq) * (Tn * Fn * 4)
                                   + (size_t)p * (TT * Fn * 4) + rem);
                    }
                }
                char* ld = (char*)&s_x[p & 1][0][0][0];
#pragma unroll
                for (int ci = 0; ci < 9; ++ci) {
                    const int c = wp + ci * 3;
                    if (c < 25)
                        *(float4*)(ld + c * 1024 + lane * 16) = vv[ci];
                }
            }

            // xg for tile p-1: read s_x[(p-1)&1], write s_xg[(p-1)&1][r][q][jj*4+ss]
            if (p >= 1 && p <= NTt) {
                const float* sx = &s_x [(p - 1) & 1][0][0][0];
                float*       so = &s_xg[(p - 1) & 1][0][0][0];
                for (int r = wp; r < TT; r += 3) {
#pragma unroll
                    for (int qq = 0; qq < 4; ++qq) {
                        const int q = qh + qq;
                        const float* xr = sx + (q * TT + r) * Fn;
                        float a0 = bias1, a1 = 0.f, a2 = 0.f, a3 = 0.f;
#pragma unroll
                        for (int k = 0; k < Fn; k += 4) {
                            const float4 cv = *(const float4*)&xr[k];
                            a0 = fmaf(cv.x, wih1[k],     a0);
                            a1 = fmaf(cv.y, wih1[k + 1], a1);
                            a2 = fmaf(cv.z, wih1[k + 2], a2);
                            a3 = fmaf(cv.w, wih1[k + 3], a3);
                        }
                        so[(r * BW + q) * 32 + jj * 4 + ss] = (a0 + a1) + (a2 + a3);
                    }
                }
            }
            __syncthreads();
        }
    }
}

extern "C" void kernel_launch(void* const* d_in, const int* in_sizes, int n_in,
                              void* d_out, int out_size, void* d_ws, size_t ws_size,
                              hipStream_t stream) {
    (void)in_sizes; (void)n_in; (void)out_size; (void)d_ws; (void)ws_size;
    const float* x     = (const float*)d_in[0];
    const float* W_ih1 = (const float*)d_in[1];
    const float* W_hh1 = (const float*)d_in[2];
    const float* b_ih1 = (const float*)d_in[3];
    const float* b_hh1 = (const float*)d_in[4];
    const float* W_ih2 = (const float*)d_in[5];
    const float* W_hh2 = (const float*)d_in[6];
    const float* b_ih2 = (const float*)d_in[7];
    const float* b_hh2 = (const float*)d_in[8];
    const float* W_fc  = (const float*)d_in[9];
    const float* b_fc  = (const float*)d_in[10];
    float* out = (float*)d_out;

    lstm_upl<<<dim3(Bn / BW), dim3(256), 0, stream>>>(x, W_ih1, W_hh1, b_ih1, b_hh1,
                                                      W_ih2, W_hh2, b_ih2, b_hh2,
                                                      W_fc, b_fc, out);
}

// Round 5
// 727.921 us; speedup vs baseline: 1.6677x; 1.0910x over previous
//
#include <hip/hip_runtime.h>

// LSTM_1030792151143: 2-layer LSTM (B=2048, T=1000, F=40, H1=8, H2=6) + tanh + FC + sigmoid.
//
// Round 7: producer v2 — kill DS-pipe contention.
//   r4 measured 480us = 1107 cy/step vs ~300 cy/step model; VALUBusy 28.8% on all 4
//   waves -> everything 70% stalled. Suspect: producers issued ~280 wave-uniform
//   ds_read_b128/phase each (16B useful per ~12cy pipe op) -> ~45% DS-pipe occupancy;
//   consumer swizzle trips queue behind them.
//   Fix: producer lane = (batch q, unit j) computes all 4 gates of unit j:
//     - s_x reads become 8-way divergent b128 (128B useful/op) -> 70 reads/phase (4x cut)
//     - s_x padded +16B/batch (stride 3216B) so the 8 addresses hit distinct bank quads
//     - xg store = one ds_write_b128 per row (vs 4 scalar writes)
//     - stage loads issued BEFORE xg compute, LDS-written after (hide HBM latency)
//   Consumer (verified, absmax 0.0) unchanged.

constexpr int Bn = 2048, Tn = 1000, Fn = 40;
constexpr int H1n = 8, H2n = 6;
constexpr int TT  = 20;                 // rows per tile (50 * 20 = 1000, no tail)
constexpr int NTt = Tn / TT;            // 50 tiles
constexpr int BW  = 8;                  // batches per block (= per consumer wave)

constexpr int SROWF  = TT * Fn + 4;     // 804 floats per batch in s_x (16B pad -> bank spread)
constexpr int SXF    = BW * SROWF;      // 6432 floats per parity buffer
constexpr int SXB    = SXF * 4;         // 25728 bytes
constexpr int NCHUNK = (SXB + 1023) / 1024;   // 26 staging chunks of 64 lanes x 16B

__device__ __forceinline__ float frcp(float x) { return __builtin_amdgcn_rcpf(x); }
__device__ __forceinline__ float fsig(float x) { return frcp(1.0f + __expf(-x)); }
__device__ __forceinline__ float ftanh(float x) {
    return fmaf(2.0f, frcp(1.0f + __expf(-2.0f * x)), -1.0f);
}

// broadcast lane ((lane & 0x18) | K) within each 32-lane half: groups of 8 lanes.
template <int K>
__device__ __forceinline__ float bswz(float v) {
    return __int_as_float(__builtin_amdgcn_ds_swizzle(__float_as_int(v), (K << 5) | 0x18));
}

__global__ __launch_bounds__(256, 1) void lstm_upl(
    const float* __restrict__ x,
    const float* __restrict__ W_ih1, const float* __restrict__ W_hh1,
    const float* __restrict__ b_ih1, const float* __restrict__ b_hh1,
    const float* __restrict__ W_ih2, const float* __restrict__ W_hh2,
    const float* __restrict__ b_ih2, const float* __restrict__ b_hh2,
    const float* __restrict__ W_fc,  const float* __restrict__ b_fc,
    float* __restrict__ out)
{
    __shared__ float s_x [2][SXF];               // 51456 B (padded x tiles)
    __shared__ float s_xg[2][TT * BW * 32];      // 40960 B ([t][q][j][gate])

    const int lane  = threadIdx.x & 63;
    const int wslot = __builtin_amdgcn_readfirstlane((int)(threadIdx.x >> 6));
    const int b0    = blockIdx.x * BW;

    // Schedule (52 phases, p = 0..51):
    //   producers: stage x tile p -> s_x[p&1]                      (p < 50)
    //              xg tile p-1: s_x[(p-1)&1] -> s_xg[(p-1)&1]      (1 <= p <= 50)
    //   consumer : run tile p-2 from s_xg[(p-2)&1]                 (p >= 2)

    if (wslot == 0) {
        // ---------------- consumer: 8 batches, unit-per-lane (unchanged) ----------------
        const int q  = lane >> 3;                 // batch in block
        const int j  = lane & 7;                  // L1 hidden unit
        const int j2 = (j < H2n) ? j : (H2n - 1); // L2 unit (lanes 6,7 duplicate unit 5)

        float wi1[H1n], wf1[H1n], wg1[H1n], wo1[H1n];
#pragma unroll
        for (int k = 0; k < H1n; ++k) {
            wi1[k] = W_hh1[(     j) * H1n + k];
            wf1[k] = W_hh1[( 8 + j) * H1n + k];
            wg1[k] = W_hh1[(16 + j) * H1n + k];
            wo1[k] = W_hh1[(24 + j) * H1n + k];
        }
        float wi2[H1n], wf2[H1n], wg2[H1n], wo2[H1n];
#pragma unroll
        for (int k = 0; k < H1n; ++k) {
            wi2[k] = W_ih2[(     j2) * H1n + k];
            wf2[k] = W_ih2[( 6 + j2) * H1n + k];
            wg2[k] = W_ih2[(12 + j2) * H1n + k];
            wo2[k] = W_ih2[(18 + j2) * H1n + k];
        }
        float vi2[H2n], vf2[H2n], vg2[H2n], vo2[H2n];
#pragma unroll
        for (int k = 0; k < H2n; ++k) {
            vi2[k] = W_hh2[(     j2) * H2n + k];
            vf2[k] = W_hh2[( 6 + j2) * H2n + k];
            vg2[k] = W_hh2[(12 + j2) * H2n + k];
            vo2[k] = W_hh2[(18 + j2) * H2n + k];
        }
        const float bi2c = b_ih2[     j2] + b_hh2[     j2];
        const float bf2c = b_ih2[ 6 + j2] + b_hh2[ 6 + j2];
        const float bg2c = b_ih2[12 + j2] + b_hh2[12 + j2];
        const float bo2c = b_ih2[18 + j2] + b_hh2[18 + j2];

        float wfc[H2n];
#pragma unroll
        for (int k = 0; k < H2n; ++k) wfc[k] = W_fc[k];
        const float bfc = b_fc[0];

        float c1 = 0.f, c2 = 0.f;
        float h1s[H1n], th1s[H1n], h2s[H2n];
#pragma unroll
        for (int k = 0; k < H1n; ++k) { h1s[k] = 0.f; th1s[k] = 0.f; }
#pragma unroll
        for (int k = 0; k < H2n; ++k) h2s[k] = 0.f;

        const int myoff = q * 32 + j * 4;         // float offset of this lane's 4 gates

        for (int p = 0; p <= NTt + 1; ++p) {
            if (p >= 2) {
                const float* xgt = &s_xg[(p - 2) & 1][0];
                float4 xg4 = *(const float4*)(xgt + myoff);          // row 0 (sync)
                for (int i = 0; i < TT; ++i) {
                    const int in = (i + 1 < TT) ? (i + 1) : i;
                    const float4 xgn = *(const float4*)(xgt + in * (BW * 32) + myoff);

                    // ---- L1: 4 gate dots (h1s from prev step's swizzles) ----
                    float ai0 = xg4.x, ai1 = 0.f, af0 = xg4.y, af1 = 0.f;
                    float ag0 = xg4.z, ag1 = 0.f, ao0 = xg4.w, ao1 = 0.f;
#pragma unroll
                    for (int k = 0; k < H1n; k += 2) {
                        ai0 = fmaf(h1s[k], wi1[k], ai0); ai1 = fmaf(h1s[k+1], wi1[k+1], ai1);
                        af0 = fmaf(h1s[k], wf1[k], af0); af1 = fmaf(h1s[k+1], wf1[k+1], af1);
                        ag0 = fmaf(h1s[k], wg1[k], ag0); ag1 = fmaf(h1s[k+1], wg1[k+1], ag1);
                        ao0 = fmaf(h1s[k], wo1[k], ao0); ao1 = fmaf(h1s[k+1], wo1[k+1], ao1);
                    }
                    const float iv = fsig (ai0 + ai1);
                    const float fv = fsig (af0 + af1);
                    const float gv = ftanh(ag0 + ag1);
                    const float ov = fsig (ao0 + ao1);
                    c1 = fmaf(fv, c1, iv * gv);
                    const float h1v  = ov * ftanh(c1);
                    const float th1v = ftanh(h1v);

                    // ---- one swizzle trip: broadcast h1/th1 within the 8-lane group ----
                    h1s[0] = bswz<0>(h1v); h1s[1] = bswz<1>(h1v);
                    h1s[2] = bswz<2>(h1v); h1s[3] = bswz<3>(h1v);
                    h1s[4] = bswz<4>(h1v); h1s[5] = bswz<5>(h1v);
                    h1s[6] = bswz<6>(h1v); h1s[7] = bswz<7>(h1v);
                    th1s[0] = bswz<0>(th1v); th1s[1] = bswz<1>(th1v);
                    th1s[2] = bswz<2>(th1v); th1s[3] = bswz<3>(th1v);
                    th1s[4] = bswz<4>(th1v); th1s[5] = bswz<5>(th1v);
                    th1s[6] = bswz<6>(th1v); th1s[7] = bswz<7>(th1v);

                    // ---- L2: h2s-partials first (fills the swizzle latency) ----
                    float bi0 = bi2c, bi1 = 0.f, bf0 = bf2c, bf1 = 0.f;
                    float bg0 = bg2c, bg1 = 0.f, bo0 = bo2c, bo1 = 0.f;
#pragma unroll
                    for (int k = 0; k < H2n; k += 2) {
                        bi0 = fmaf(h2s[k], vi2[k], bi0); bi1 = fmaf(h2s[k+1], vi2[k+1], bi1);
                        bf0 = fmaf(h2s[k], vf2[k], bf0); bf1 = fmaf(h2s[k+1], vf2[k+1], bf1);
                        bg0 = fmaf(h2s[k], vg2[k], bg0); bg1 = fmaf(h2s[k+1], vg2[k+1], bg1);
                        bo0 = fmaf(h2s[k], vo2[k], bo0); bo1 = fmaf(h2s[k+1], vo2[k+1], bo1);
                    }
#pragma unroll
                    for (int k = 0; k < H1n; k += 2) {
                        bi0 = fmaf(th1s[k], wi2[k], bi0); bi1 = fmaf(th1s[k+1], wi2[k+1], bi1);
                        bf0 = fmaf(th1s[k], wf2[k], bf0); bf1 = fmaf(th1s[k+1], wf2[k+1], bf1);
                        bg0 = fmaf(th1s[k], wg2[k], bg0); bg1 = fmaf(th1s[k+1], wg2[k+1], bg1);
                        bo0 = fmaf(th1s[k], wo2[k], bo0); bo1 = fmaf(th1s[k+1], wo2[k+1], bo1);
                    }
                    const float i2v = fsig (bi0 + bi1);
                    const float f2v = fsig (bf0 + bf1);
                    const float g2v = ftanh(bg0 + bg1);
                    const float o2v = fsig (bo0 + bo1);
                    c2 = fmaf(f2v, c2, i2v * g2v);
                    const float h2v = o2v * ftanh(c2);

                    h2s[0] = bswz<0>(h2v); h2s[1] = bswz<1>(h2v);
                    h2s[2] = bswz<2>(h2v); h2s[3] = bswz<3>(h2v);
                    h2s[4] = bswz<4>(h2v); h2s[5] = bswz<5>(h2v);

                    xg4 = xgn;
                }
            }
            __syncthreads();
        }

        if (j == 0) {                              // lanes 0,8,...,56 -> out[b0 + q]
            float a = bfc;
#pragma unroll
            for (int k = 0; k < H2n; ++k) a = fmaf(ftanh(h2s[k]), wfc[k], a);
            out[b0 + q] = fsig(a);
        }
    } else {
        // ---------------- producers v2: lane = (batch q, unit j), 4 gates/lane ----------
        const int wp = wslot - 1;                  // 0..2 (row stripe r == wp mod 3)
        const int q  = lane >> 3;                  // batch
        const int j  = lane & 7;                   // L1 unit

        float wI[Fn], wF[Fn], wG[Fn], wO[Fn];      // W_ih1 rows j, 8+j, 16+j, 24+j
#pragma unroll
        for (int k = 0; k < Fn; ++k) {
            wI[k] = W_ih1[(     j) * Fn + k];
            wF[k] = W_ih1[( 8 + j) * Fn + k];
            wG[k] = W_ih1[(16 + j) * Fn + k];
            wO[k] = W_ih1[(24 + j) * Fn + k];
        }
        const float bI = b_ih1[     j] + b_hh1[     j];
        const float bF = b_ih1[ 8 + j] + b_hh1[ 8 + j];
        const float bG = b_ih1[16 + j] + b_hh1[16 + j];
        const float bO = b_ih1[24 + j] + b_hh1[24 + j];

        const char* xcb = (const char*)x;

        for (int p = 0; p <= NTt + 1; ++p) {
            // 1) issue stage loads for tile p (kept in regs; LDS-written after compute)
            float4 vv[9];
            if (p < NTt) {
#pragma unroll
                for (int ci = 0; ci < 9; ++ci) {
                    const int c = wp + ci * 3;
                    if (c < NCHUNK) {
                        const int o = c * 1024 + lane * 16;     // byte offset in s_x buffer
                        if (o < SXB) {
                            const int qq  = o / (SROWF * 4);    // batch (3216 B stride)
                            int       rem = o - qq * (SROWF * 4);
                            if (rem > TT * Fn * 4 - 16) rem = TT * Fn * 4 - 16;  // pad clamp
                            vv[ci] = *(const float4*)(xcb
                                       + (size_t)(b0 + qq) * (Tn * Fn * 4)
                                       + (size_t)p * (TT * Fn * 4) + rem);
                        }
                    }
                }
            }

            // 2) xg for tile p-1: 8-way-divergent b128 reads, one b128 write per row
            if (p >= 1 && p <= NTt) {
                const float* xq = &s_x[(p - 1) & 1][0] + q * SROWF;
                float*       so = &s_xg[(p - 1) & 1][0];
                for (int r = wp; r < TT; r += 3) {
                    const float* xr = xq + r * Fn;
                    float i0 = bI, i1 = 0.f, i2 = 0.f, i3 = 0.f;
                    float f0 = bF, f1 = 0.f, f2 = 0.f, f3 = 0.f;
                    float g0 = bG, g1 = 0.f, g2 = 0.f, g3 = 0.f;
                    float o0 = bO, o1 = 0.f, o2 = 0.f, o3 = 0.f;
#pragma unroll
                    for (int k = 0; k < Fn; k += 4) {
                        const float4 cv = *(const float4*)&xr[k];
                        i0 = fmaf(cv.x, wI[k],     i0); i1 = fmaf(cv.y, wI[k + 1], i1);
                        i2 = fmaf(cv.z, wI[k + 2], i2); i3 = fmaf(cv.w, wI[k + 3], i3);
                        f0 = fmaf(cv.x, wF[k],     f0); f1 = fmaf(cv.y, wF[k + 1], f1);
                        f2 = fmaf(cv.z, wF[k + 2], f2); f3 = fmaf(cv.w, wF[k + 3], f3);
                        g0 = fmaf(cv.x, wG[k],     g0); g1 = fmaf(cv.y, wG[k + 1], g1);
                        g2 = fmaf(cv.z, wG[k + 2], g2); g3 = fmaf(cv.w, wG[k + 3], g3);
                        o0 = fmaf(cv.x, wO[k],     o0); o1 = fmaf(cv.y, wO[k + 1], o1);
                        o2 = fmaf(cv.z, wO[k + 2], o2); o3 = fmaf(cv.w, wO[k + 3], o3);
                    }
                    float4 r4;
                    r4.x = (i0 + i1) + (i2 + i3);
                    r4.y = (f0 + f1) + (f2 + f3);
                    r4.z = (g0 + g1) + (g2 + g3);
                    r4.w = (o0 + o1) + (o2 + o3);
                    *(float4*)&so[(r * BW + q) * 32 + j * 4] = r4;   // 1KB/wave, conflict-free
                }
            }

            // 3) LDS-write the staged tile (vmcnt wait lands here, hidden under step 2)
            if (p < NTt) {
                char* ld = (char*)&s_x[p & 1][0];
#pragma unroll
                for (int ci = 0; ci < 9; ++ci) {
                    const int c = wp + ci * 3;
                    if (c < NCHUNK) {
                        const int o = c * 1024 + lane * 16;
                        if (o < SXB) *(float4*)(ld + o) = vv[ci];
                    }
                }
            }
            __syncthreads();
        }
    }
}

extern "C" void kernel_launch(void* const* d_in, const int* in_sizes, int n_in,
                              void* d_out, int out_size, void* d_ws, size_t ws_size,
                              hipStream_t stream) {
    (void)in_sizes; (void)n_in; (void)out_size; (void)d_ws; (void)ws_size;
    const float* x     = (const float*)d_in[0];
    const float* W_ih1 = (const float*)d_in[1];
    const float* W_hh1 = (const float*)d_in[2];
    const float* b_ih1 = (const float*)d_in[3];
    const float* b_hh1 = (const float*)d_in[4];
    const float* W_ih2 = (const float*)d_in[5];
    const float* W_hh2 = (const float*)d_in[6];
    const float* b_ih2 = (const float*)d_in[7];
    const float* b_hh2 = (const float*)d_in[8];
    const float* W_fc  = (const float*)d_in[9];
    const float* b_fc  = (const float*)d_in[10];
    float* out = (float*)d_out;

    lstm_upl<<<dim3(Bn / BW), dim3(256), 0, stream>>>(x, W_ih1, W_hh1, b_ih1, b_hh1,
                                                      W_ih2, W_hh2, b_ih2, b_hh2,
                                                      W_fc, b_fc, out);
}